// Round 1
// baseline (550.403 us; speedup 1.0000x reference)
//
#include <hip/hip_runtime.h>
#include <math.h>

#define NEGC (-10000.0f)

// Problem dims (fixed by setup_inputs)
// B=64, T_seq=256, T_mel=2048, D=80; SSIM out = 2038 x 70

struct Ws {
  double ssim_sum;          // zeroed in k1 (dur block), atomicAdd in k2
  double dur_sum;
  double spec_part[256];    // per (batch, quarter) partial sums of masked sq diff
  float  mdn_val[64];       // alpha_last per batch
  float  mnT[256], mxT[256], mnO[256], mxO[256];  // per (batch*4+part) min/max partials
  float  alpha[64 * 256];   // MDN checkpoint (optional, if ws big enough)
};

__device__ __forceinline__ float lae(float a, float b) {
  // logaddexp(a,b) = max + log(1 + exp(-|a-b|))
  float m = fmaxf(a, b);
  float d = fabsf(a - b);
  return m + __logf(1.0f + __expf(-d));
}

__device__ __forceinline__ float pick4(float4 f, int e) {
  return e == 0 ? f.x : e == 1 ? f.y : e == 2 ? f.z : f.w;
}

// Run MDN recursion steps t = ts..te (inclusive). Lane `lane` owns states
// s = 4*lane .. 4*lane+3 (contiguous). row0 points at logp row s=4*lane.
__device__ void mdn_steps(const float* __restrict__ row0, int lane,
                          float& a0, float& a1, float& a2, float& a3,
                          int ts, int te) {
  if (te < ts) return;
  const float* r1 = row0 + 2048;
  const float* r2 = row0 + 2 * 2048;
  const float* r3 = row0 + 3 * 2048;
  int c = ts >> 2, cend = te >> 2;
  float4 f0 = *(const float4*)(row0 + 4 * c);
  float4 f1 = *(const float4*)(r1 + 4 * c);
  float4 f2 = *(const float4*)(r2 + 4 * c);
  float4 f3 = *(const float4*)(r3 + 4 * c);
  for (; c <= cend; ++c) {
    float4 g0 = f0, g1 = f1, g2 = f2, g3 = f3;
    if (c < cend) {  // prefetch next chunk (hides latency under 4 steps)
      int nc = 4 * (c + 1);
      f0 = *(const float4*)(row0 + nc);
      f1 = *(const float4*)(r1 + nc);
      f2 = *(const float4*)(r2 + nc);
      f3 = *(const float4*)(r3 + nc);
    }
    int t0c = 4 * c;
#pragma unroll
    for (int e = 0; e < 4; ++e) {
      int t = t0c + e;
      if (t < ts || t > te) continue;  // wave-uniform guard (boundary chunks only)
      float am1 = __shfl_up(a3, 1u);   // alpha[4*lane - 1] from lane-1
      am1 = (lane == 0) ? NEGC : am1;
      float n0 = lae(a0, am1) + (pick4(g0, e) + 1e-4f);
      float n1 = lae(a1, a0)  + (pick4(g1, e) + 1e-4f);
      float n2 = lae(a2, a1)  + (pick4(g2, e) + 1e-4f);
      float n3 = lae(a3, a2)  + (pick4(g3, e) + 1e-4f);
      a0 = n0; a1 = n1; a2 = n2; a3 = n3;
    }
  }
}

// ---------------- K1: MDN first half || per-batch min/max + spec MSE || dur ----------------
__global__ __launch_bounds__(256) void altts_k1(
    const float* __restrict__ logp,
    const float* __restrict__ deco, const float* __restrict__ dect,
    const float* __restrict__ duro, const float* __restrict__ durt,
    const int* __restrict__ mel_lens, const int* __restrict__ inp_lens,
    Ws* __restrict__ ws, int split) {
  __shared__ float L[5][4];
  int bid = blockIdx.x;
  int tid = threadIdx.x;

  if (bid < 64) {  // MDN part 1 (steps 1..min(split,T))
    if (split <= 0) return;
    if (tid >= 64) return;
    __builtin_amdgcn_s_setprio(1);
    int b = bid;
    int T = mel_lens[b] - 1;
    const float* row0 = logp + ((size_t)(b * 256 + 4 * tid)) * 2048;
    float a0 = (tid == 0) ? row0[0] : NEGC;
    float a1 = NEGC, a2 = NEGC, a3 = NEGC;
    int te = T < split ? T : split;
    mdn_steps(row0, tid, a0, a1, a2, a3, 1, te);
    float* ck = ws->alpha + b * 256 + 4 * tid;
    ck[0] = a0; ck[1] = a1; ck[2] = a2; ck[3] = a3;
    if (T <= split) {  // finished already (mel_len == 1024)
      int ss_ = inp_lens[b] - 1;
      if ((ss_ >> 2) == tid) {
        int e = ss_ & 3;
        ws->mdn_val[b] = (e == 0) ? a0 : (e == 1) ? a1 : (e == 2) ? a2 : a3;
      }
    }
    return;
  }

  if (bid < 320) {  // min/max + spec partial: 4 blocks per batch, 512 rows each
    int idx = bid - 64, b = idx >> 2, part = idx & 3;
    int len = mel_lens[b];
    int rbeg = part * 512;
    int rcnt = len - rbeg; rcnt = rcnt < 0 ? 0 : (rcnt > 512 ? 512 : rcnt);
    float mnT = __builtin_inff(), mxT = -__builtin_inff();
    float mnO = __builtin_inff(), mxO = -__builtin_inff();
    float ssum = 0.f;
    if (rcnt > 0) {
      const float4* po = (const float4*)(deco + ((size_t)(b * 2048 + rbeg)) * 80);
      const float4* pt = (const float4*)(dect + ((size_t)(b * 2048 + rbeg)) * 80);
      int n4 = rcnt * 20;  // rcnt*80/4
      for (int i = tid; i < n4; i += 256) {
        float4 vo = po[i], vt = pt[i];
        mnO = fminf(mnO, fminf(fminf(vo.x, vo.y), fminf(vo.z, vo.w)));
        mxO = fmaxf(mxO, fmaxf(fmaxf(vo.x, vo.y), fmaxf(vo.z, vo.w)));
        mnT = fminf(mnT, fminf(fminf(vt.x, vt.y), fminf(vt.z, vt.w)));
        mxT = fmaxf(mxT, fmaxf(fmaxf(vt.x, vt.y), fmaxf(vt.z, vt.w)));
        float dx = vo.x - vt.x, dy = vo.y - vt.y, dz = vo.z - vt.z, dw = vo.w - vt.w;
        ssum += dx * dx + dy * dy + dz * dz + dw * dw;
      }
    }
    for (int o = 32; o; o >>= 1) {
      mnT = fminf(mnT, __shfl_xor(mnT, o));
      mxT = fmaxf(mxT, __shfl_xor(mxT, o));
      mnO = fminf(mnO, __shfl_xor(mnO, o));
      mxO = fmaxf(mxO, __shfl_xor(mxO, o));
      ssum += __shfl_xor(ssum, o);
    }
    int w = tid >> 6;
    if ((tid & 63) == 0) { L[0][w] = mnT; L[1][w] = mxT; L[2][w] = mnO; L[3][w] = mxO; L[4][w] = ssum; }
    __syncthreads();
    if (tid == 0) {
      mnT = fminf(fminf(L[0][0], L[0][1]), fminf(L[0][2], L[0][3]));
      mxT = fmaxf(fmaxf(L[1][0], L[1][1]), fmaxf(L[1][2], L[1][3]));
      mnO = fminf(fminf(L[2][0], L[2][1]), fminf(L[2][2], L[2][3]));
      mxO = fmaxf(fmaxf(L[3][0], L[3][1]), fmaxf(L[3][2], L[3][3]));
      ssum = L[4][0] + L[4][1] + L[4][2] + L[4][3];
      ws->mnT[idx] = mnT; ws->mxT[idx] = mxT; ws->mnO[idx] = mnO; ws->mxO[idx] = mxO;
      ws->spec_part[idx] = (double)ssum;
    }
    return;
  }

  // dur MSE block + zero the ssim accumulator (runs before k2 uses it)
  {
    float ssum = 0.f;
    for (int i = tid; i < 64 * 256; i += 256) {
      int b2 = i >> 8, s2 = i & 255;
      if (s2 < inp_lens[b2]) { float d = duro[i] - durt[i]; ssum += d * d; }
    }
    for (int o = 32; o; o >>= 1) ssum += __shfl_xor(ssum, o);
    int w = tid >> 6;
    if ((tid & 63) == 0) L[4][w] = ssum;
    __syncthreads();
    if (tid == 0) {
      ws->dur_sum = (double)(L[4][0] + L[4][1] + L[4][2] + L[4][3]);
      ws->ssim_sum = 0.0;
    }
  }
}

// ---------------- K2: MDN second half || SSIM conv tiles ----------------
constexpr float G11[11] = {
  0.00102838f, 0.00759876f, 0.03600077f, 0.10936070f, 0.21300554f,
  0.26601172f,
  0.21300554f, 0.10936070f, 0.03600077f, 0.00759876f, 0.00102838f};

__global__ __launch_bounds__(256) void altts_k2(
    const float* __restrict__ logp,
    const float* __restrict__ deco, const float* __restrict__ dect,
    const int* __restrict__ mel_lens, const int* __restrict__ inp_lens,
    Ws* __restrict__ ws, int split) {
  __shared__ float cc[5 * 2940];  // column-conv buffer [5][42][70]
  __shared__ float R[4];
  int bid = blockIdx.x, tid = threadIdx.x;

  if (bid < 64) {  // MDN part 2 (steps split+1..T)
    if (tid >= 64) return;
    __builtin_amdgcn_s_setprio(1);
    int b = bid;
    int T = mel_lens[b] - 1;
    if (split > 0 && T <= split) return;  // already recorded in k1
    const float* row0 = logp + ((size_t)(b * 256 + 4 * tid)) * 2048;
    float a0, a1, a2, a3;
    int ts;
    if (split > 0) {
      const float* ck = ws->alpha + b * 256 + 4 * tid;
      a0 = ck[0]; a1 = ck[1]; a2 = ck[2]; a3 = ck[3];
      ts = split + 1;
    } else {
      a0 = (tid == 0) ? row0[0] : NEGC; a1 = a2 = a3 = NEGC;
      ts = 1;
    }
    mdn_steps(row0, tid, a0, a1, a2, a3, ts, T);
    int ss_ = inp_lens[b] - 1;
    if ((ss_ >> 2) == tid) {
      int e = ss_ & 3;
      ws->mdn_val[b] = (e == 0) ? a0 : (e == 1) ? a1 : (e == 2) ? a2 : a3;
    }
    return;
  }

  // SSIM conv tile: 64 tiles of 32 output rows per batch
  int cix = bid - 64;
  int b = cix >> 6, tile = cix & 63;
  int r0 = tile * 32;
  int nrows = 2038 - r0; nrows = nrows > 32 ? 32 : nrows;
  int nin = nrows + 10;
  int len = mel_lens[b];
  float mnT = fminf(fminf(ws->mnT[4 * b], ws->mnT[4 * b + 1]), fminf(ws->mnT[4 * b + 2], ws->mnT[4 * b + 3]));
  float mxT = fmaxf(fmaxf(ws->mxT[4 * b], ws->mxT[4 * b + 1]), fmaxf(ws->mxT[4 * b + 2], ws->mxT[4 * b + 3]));
  float mnO = fminf(fminf(ws->mnO[4 * b], ws->mnO[4 * b + 1]), fminf(ws->mnO[4 * b + 2], ws->mnO[4 * b + 3]));
  float mxO = fmaxf(fmaxf(ws->mxO[4 * b], ws->mxO[4 * b + 1]), fmaxf(ws->mxO[4 * b + 2], ws->mxO[4 * b + 3]));
  if (len < 2048) { mxT = fmaxf(mxT, 0.f); mxO = fmaxf(mxO, 0.f); }  // where(mask,x,0) max
  float sT = 1.0f / (mxT - mnT + 1e-8f);
  float sO = 1.0f / (mxO - mnO + 1e-8f);
  const float* po = deco + (size_t)b * 2048 * 80;
  const float* pt = dect + (size_t)b * 2048 * 80;

  // Phase A: column conv (width 80 -> 70) for nin input rows, 5 channels
  for (int p = tid; p < nin * 70; p += 256) {
    int r = p / 70, j = p - 70 * r;
    int grow = r0 + r;
    float s0 = 0, s1 = 0, s2 = 0, s3 = 0, s4 = 0;
    if (grow < len) {  // masked rows are exactly 0 -> all sums 0, skip loads
      const float* ro = po + (size_t)grow * 80 + j;
      const float* rt = pt + (size_t)grow * 80 + j;
#pragma unroll
      for (int k = 0; k < 11; ++k) {
        float tn = (rt[k] - mnT) * sT;
        float on = (ro[k] - mnO) * sO;
        float g = G11[k];
        s0 = fmaf(g, tn, s0);
        s1 = fmaf(g, on, s1);
        s2 = fmaf(g * tn, tn, s2);
        s3 = fmaf(g * on, on, s3);
        s4 = fmaf(g * tn, on, s4);
      }
    }
    cc[p] = s0; cc[2940 + p] = s1; cc[2 * 2940 + p] = s2;
    cc[3 * 2940 + p] = s3; cc[4 * 2940 + p] = s4;
  }
  __syncthreads();

  // Phase B: row conv + SSIM formula + accumulate
  float acc = 0.f;
  for (int q = tid; q < nrows * 70; q += 256) {
    int i = q / 70, j = q - 70 * i;
    float mx = 0, my = 0, xx = 0, yy = 0, xy = 0;
#pragma unroll
    for (int k = 0; k < 11; ++k) {
      float g = G11[k];
      int o = (i + k) * 70 + j;
      mx = fmaf(g, cc[o], mx);
      my = fmaf(g, cc[2940 + o], my);
      xx = fmaf(g, cc[2 * 2940 + o], xx);
      yy = fmaf(g, cc[3 * 2940 + o], yy);
      xy = fmaf(g, cc[4 * 2940 + o], xy);
    }
    float vx = xx - mx * mx, vy = yy - my * my, vxy = xy - mx * my;
    float cs = (2.f * vxy + 9e-4f) / (vx + vy + 9e-4f);
    float lum = (2.f * mx * my + 1e-4f) / (mx * mx + my * my + 1e-4f);
    acc += lum * cs;
  }
  for (int o = 32; o; o >>= 1) acc += __shfl_xor(acc, o);
  if ((tid & 63) == 0) R[tid >> 6] = acc;
  __syncthreads();
  if (tid == 0) atomicAdd(&ws->ssim_sum, (double)(R[0] + R[1] + R[2] + R[3]));
}

// ---------------- K3: finalize scalar ----------------
__global__ __launch_bounds__(256) void altts_k3(
    const int* __restrict__ mel_lens, const int* __restrict__ inp_lens,
    Ws* __restrict__ ws, float* __restrict__ out) {
  __shared__ double LD[4][4];
  int tid = threadIdx.x;
  double sp = ws->spec_part[tid];
  double md = 0.0, ml = 0.0, il = 0.0;
  if (tid < 64) {
    md = (double)ws->mdn_val[tid];
    ml = (double)mel_lens[tid];
    il = (double)inp_lens[tid];
  }
  for (int o = 32; o; o >>= 1) {
    sp += __shfl_xor(sp, o);
    md += __shfl_xor(md, o);
    ml += __shfl_xor(ml, o);
    il += __shfl_xor(il, o);
  }
  int w = tid >> 6;
  if ((tid & 63) == 0) { LD[w][0] = sp; LD[w][1] = md; LD[w][2] = ml; LD[w][3] = il; }
  __syncthreads();
  if (tid == 0) {
    sp = LD[0][0] + LD[1][0] + LD[2][0] + LD[3][0];
    md = LD[0][1] + LD[1][1] + LD[2][1] + LD[3][1];
    ml = LD[0][2] + LD[1][2] + LD[2][2] + LD[3][2];
    il = LD[0][3] + LD[1][3] + LD[2][3] + LD[3][3];
    double spec = sp / (ml * 80.0);
    double dur = ws->dur_sum / il;
    double mdn = -(md / 64.0) / 256.0;
    double sm = ws->ssim_sum / (64.0 * 2038.0 * 70.0);
    double sl = 1.0 - sm;
    sl = sl < 0.0 ? 0.0 : (sl > 1.0 ? 1.0 : sl);
    out[0] = (float)(spec + sl + dur + mdn);
  }
}

extern "C" void kernel_launch(void* const* d_in, const int* in_sizes, int n_in,
                              void* d_out, int out_size, void* d_ws, size_t ws_size,
                              hipStream_t stream) {
  const float* logp = (const float*)d_in[0];
  const float* deco = (const float*)d_in[1];
  const float* dect = (const float*)d_in[2];
  const float* duro = (const float*)d_in[3];
  const float* durt = (const float*)d_in[4];
  const int* mel_lens = (const int*)d_in[5];
  const int* inp_lens = (const int*)d_in[6];
  Ws* ws = (Ws*)d_ws;
  // Split the serial MDN chain across K1/K2 (checkpoint in ws) so its second
  // half overlaps the SSIM conv. If ws is too small for the checkpoint, run
  // the whole chain in K2 (split=0).
  int split = (ws_size >= sizeof(Ws)) ? 1023 : 0;
  hipLaunchKernelGGL(altts_k1, dim3(321), dim3(256), 0, stream,
                     logp, deco, dect, duro, durt, mel_lens, inp_lens, ws, split);
  hipLaunchKernelGGL(altts_k2, dim3(64 + 64 * 64), dim3(256), 0, stream,
                     logp, deco, dect, mel_lens, inp_lens, ws, split);
  hipLaunchKernelGGL(altts_k3, dim3(1), dim3(256), 0, stream,
                     mel_lens, inp_lens, ws, (float*)d_out);
}

// Round 3
// 269.780 us; speedup vs baseline: 2.0402x; 2.0402x over previous
//
#include <hip/hip_runtime.h>
#include <math.h>

#define NEGC    (-10000.0f)
#define INV_LN2 1.44269504088896f
#define LN2     0.693147180559945f
#define NEG2    (-14426.9504f)          // NEGC * INV_LN2
#define EPS2    (1.44269504e-4f)        // 1e-4 * INV_LN2

// Problem dims (fixed by setup_inputs)
// B=64, T_seq=256, T_mel=2048, D=80; SSIM out = 2038 x 70

struct Ws {
  double ssim_sum;          // zeroed in k1 (dur block), atomicAdd in k2
  double dur_sum;
  double spec_part[256];    // per (batch, quarter) partial sums of masked sq diff
  float  mdn_val[64];       // alpha_last per batch (natural-log domain)
  float  mnT[256], mxT[256], mnO[256], mxO[256];  // per (batch*4+part) min/max partials
  float  alpha[64 * 256];   // MDN checkpoint (log2 domain)
};

__device__ __forceinline__ float lae2(float a, float b) {
  // log2-domain logaddexp: max + log2(1 + 2^-|a-b|)  (v_exp_f32/v_log_f32 direct)
  float m = fmaxf(a, b);
  float d = fabsf(a - b);
  return m + __builtin_amdgcn_logf(1.0f + __builtin_amdgcn_exp2f(-d));
}

__device__ __forceinline__ float pick4(float4 f, int e) {
  return e == 0 ? f.x : e == 1 ? f.y : e == 2 ? f.z : f.w;
}

// Run MDN recursion steps t = ts..te (inclusive), log2 domain. Lane `lane`
// owns states s = 4*lane .. 4*lane+3. row0 points at logp row s=4*lane.
// Deep register prefetch: D=8 chunks (32 steps) ahead to cover ~900cy HBM miss.
__device__ void mdn_steps(const float* __restrict__ row0, int lane,
                          float& a0, float& a1, float& a2, float& a3,
                          int ts, int te) {
  if (te < ts) return;
  const float* r1 = row0 + 2048;
  const float* r2 = row0 + 2 * 2048;
  const float* r3 = row0 + 3 * 2048;
  const int c0 = ts >> 2, cend = te >> 2;
  constexpr int D = 8;
  float4 pA[D], pB[D], pC[D], pD[D];
#pragma unroll
  for (int sl = 0; sl < D; ++sl) {
    int c = c0 + sl; c = c > cend ? cend : c;
    pA[sl] = *(const float4*)(row0 + 4 * c);
    pB[sl] = *(const float4*)(r1 + 4 * c);
    pC[sl] = *(const float4*)(r2 + 4 * c);
    pD[sl] = *(const float4*)(r3 + 4 * c);
  }

  auto STEP = [&](float g0e, float g1e, float g2e, float g3e) {
    float am1 = __shfl_up(a3, 1u);
    am1 = (lane == 0) ? NEG2 : am1;
    float n0 = lae2(a0, am1) + fmaf(g0e, INV_LN2, EPS2);
    float n1 = lae2(a1, a0)  + fmaf(g1e, INV_LN2, EPS2);
    float n2 = lae2(a2, a1)  + fmaf(g2e, INV_LN2, EPS2);
    float n3 = lae2(a3, a2)  + fmaf(g3e, INV_LN2, EPS2);
    a0 = n0; a1 = n1; a2 = n2; a3 = n3;
  };

  for (int cb = c0; cb <= cend; cb += D) {
#pragma unroll
    for (int sl = 0; sl < D; ++sl) {
      const int c = cb + sl;
      if (c > cend) break;
      float4 g0 = pA[sl], g1 = pB[sl], g2 = pC[sl], g3 = pD[sl];
      const int pc = c + D;
      if (pc <= cend) {  // prefetch chunk c+D into this slot
        pA[sl] = *(const float4*)(row0 + 4 * pc);
        pB[sl] = *(const float4*)(r1 + 4 * pc);
        pC[sl] = *(const float4*)(r2 + 4 * pc);
        pD[sl] = *(const float4*)(r3 + 4 * pc);
      }
      const int t0c = 4 * c;
      if (t0c >= ts && t0c + 3 <= te) {  // interior chunk: no per-t guards
#pragma unroll
        for (int e = 0; e < 4; ++e)
          STEP(pick4(g0, e), pick4(g1, e), pick4(g2, e), pick4(g3, e));
      } else {
#pragma unroll
        for (int e = 0; e < 4; ++e) {
          int t = t0c + e;
          if (t < ts || t > te) continue;
          STEP(pick4(g0, e), pick4(g1, e), pick4(g2, e), pick4(g3, e));
        }
      }
    }
  }
}

// ---------------- K1: MDN first half || per-batch min/max + spec MSE || dur ----------------
__global__ __launch_bounds__(256) void altts_k1(
    const float* __restrict__ logp,
    const float* __restrict__ deco, const float* __restrict__ dect,
    const float* __restrict__ duro, const float* __restrict__ durt,
    const int* __restrict__ mel_lens, const int* __restrict__ inp_lens,
    Ws* __restrict__ ws, int split) {
  __shared__ float L[5][4];
  int bid = blockIdx.x;
  int tid = threadIdx.x;

  if (bid < 64) {  // MDN part 1 (steps 1..min(split,T))
    if (split <= 0) return;
    if (tid >= 64) return;
    __builtin_amdgcn_s_setprio(1);
    int b = bid;
    int T = mel_lens[b] - 1;
    const float* row0 = logp + ((size_t)(b * 256 + 4 * tid)) * 2048;
    float a0 = (tid == 0) ? row0[0] * INV_LN2 : NEG2;
    float a1 = NEG2, a2 = NEG2, a3 = NEG2;
    int te = T < split ? T : split;
    mdn_steps(row0, tid, a0, a1, a2, a3, 1, te);
    float* ck = ws->alpha + b * 256 + 4 * tid;
    ck[0] = a0; ck[1] = a1; ck[2] = a2; ck[3] = a3;
    if (T <= split) {  // finished already (mel_len <= split+1)
      int ss_ = inp_lens[b] - 1;
      if ((ss_ >> 2) == tid) {
        int e = ss_ & 3;
        float v = (e == 0) ? a0 : (e == 1) ? a1 : (e == 2) ? a2 : a3;
        ws->mdn_val[b] = v * LN2;
      }
    }
    return;
  }

  if (bid < 320) {  // min/max + spec partial: 4 blocks per batch, 512 rows each
    int idx = bid - 64, b = idx >> 2, part = idx & 3;
    int len = mel_lens[b];
    int rbeg = part * 512;
    int rcnt = len - rbeg; rcnt = rcnt < 0 ? 0 : (rcnt > 512 ? 512 : rcnt);
    float mnT = __builtin_inff(), mxT = -__builtin_inff();
    float mnO = __builtin_inff(), mxO = -__builtin_inff();
    float ssum = 0.f;
    if (rcnt > 0) {
      const float4* po = (const float4*)(deco + ((size_t)(b * 2048 + rbeg)) * 80);
      const float4* pt = (const float4*)(dect + ((size_t)(b * 2048 + rbeg)) * 80);
      int n4 = rcnt * 20;  // rcnt*80/4
      for (int i = tid; i < n4; i += 256) {
        float4 vo = po[i], vt = pt[i];
        mnO = fminf(mnO, fminf(fminf(vo.x, vo.y), fminf(vo.z, vo.w)));
        mxO = fmaxf(mxO, fmaxf(fmaxf(vo.x, vo.y), fmaxf(vo.z, vo.w)));
        mnT = fminf(mnT, fminf(fminf(vt.x, vt.y), fminf(vt.z, vt.w)));
        mxT = fmaxf(mxT, fmaxf(fmaxf(vt.x, vt.y), fmaxf(vt.z, vt.w)));
        float dx = vo.x - vt.x, dy = vo.y - vt.y, dz = vo.z - vt.z, dw = vo.w - vt.w;
        ssum += dx * dx + dy * dy + dz * dz + dw * dw;
      }
    }
    for (int o = 32; o; o >>= 1) {
      mnT = fminf(mnT, __shfl_xor(mnT, o));
      mxT = fmaxf(mxT, __shfl_xor(mxT, o));
      mnO = fminf(mnO, __shfl_xor(mnO, o));
      mxO = fmaxf(mxO, __shfl_xor(mxO, o));
      ssum += __shfl_xor(ssum, o);
    }
    int w = tid >> 6;
    if ((tid & 63) == 0) { L[0][w] = mnT; L[1][w] = mxT; L[2][w] = mnO; L[3][w] = mxO; L[4][w] = ssum; }
    __syncthreads();
    if (tid == 0) {
      mnT = fminf(fminf(L[0][0], L[0][1]), fminf(L[0][2], L[0][3]));
      mxT = fmaxf(fmaxf(L[1][0], L[1][1]), fmaxf(L[1][2], L[1][3]));
      mnO = fminf(fminf(L[2][0], L[2][1]), fminf(L[2][2], L[2][3]));
      mxO = fmaxf(fmaxf(L[3][0], L[3][1]), fmaxf(L[3][2], L[3][3]));
      ssum = L[4][0] + L[4][1] + L[4][2] + L[4][3];
      ws->mnT[idx] = mnT; ws->mxT[idx] = mxT; ws->mnO[idx] = mnO; ws->mxO[idx] = mxO;
      ws->spec_part[idx] = (double)ssum;
    }
    return;
  }

  // dur MSE block + zero the ssim accumulator (runs before k2 uses it)
  {
    float ssum = 0.f;
    for (int i = tid; i < 64 * 256; i += 256) {
      int b2 = i >> 8, s2 = i & 255;
      if (s2 < inp_lens[b2]) { float d = duro[i] - durt[i]; ssum += d * d; }
    }
    for (int o = 32; o; o >>= 1) ssum += __shfl_xor(ssum, o);
    int w = tid >> 6;
    if ((tid & 63) == 0) L[4][w] = ssum;
    __syncthreads();
    if (tid == 0) {
      ws->dur_sum = (double)(L[4][0] + L[4][1] + L[4][2] + L[4][3]);
      ws->ssim_sum = 0.0;
    }
  }
}

// ---------------- K2: MDN second half || SSIM conv tiles ----------------
constexpr float G11[11] = {
  0.00102838f, 0.00759876f, 0.03600077f, 0.10936070f, 0.21300554f,
  0.26601172f,
  0.21300554f, 0.10936070f, 0.03600077f, 0.00759876f, 0.00102838f};

__global__ __launch_bounds__(256) void altts_k2(
    const float* __restrict__ logp,
    const float* __restrict__ deco, const float* __restrict__ dect,
    const int* __restrict__ mel_lens, const int* __restrict__ inp_lens,
    Ws* __restrict__ ws, int split) {
  __shared__ float cc[5 * 2940];  // column-conv buffer [5][42][70]
  __shared__ float R[4];
  int bid = blockIdx.x, tid = threadIdx.x;

  if (bid < 64) {  // MDN part 2 (steps split+1..T)
    if (tid >= 64) return;
    __builtin_amdgcn_s_setprio(1);
    int b = bid;
    int T = mel_lens[b] - 1;
    if (split > 0 && T <= split) return;  // already recorded in k1
    const float* row0 = logp + ((size_t)(b * 256 + 4 * tid)) * 2048;
    float a0, a1, a2, a3;
    int ts;
    if (split > 0) {
      const float* ck = ws->alpha + b * 256 + 4 * tid;
      a0 = ck[0]; a1 = ck[1]; a2 = ck[2]; a3 = ck[3];
      ts = split + 1;
    } else {
      a0 = (tid == 0) ? row0[0] * INV_LN2 : NEG2; a1 = a2 = a3 = NEG2;
      ts = 1;
    }
    mdn_steps(row0, tid, a0, a1, a2, a3, ts, T);
    int ss_ = inp_lens[b] - 1;
    if ((ss_ >> 2) == tid) {
      int e = ss_ & 3;
      float v = (e == 0) ? a0 : (e == 1) ? a1 : (e == 2) ? a2 : a3;
      ws->mdn_val[b] = v * LN2;
    }
    return;
  }

  // SSIM conv tile: 64 tiles of 32 output rows per batch
  int cix = bid - 64;
  int b = cix >> 6, tile = cix & 63;
  int r0 = tile * 32;
  int nrows = 2038 - r0; nrows = nrows > 32 ? 32 : nrows;
  int nin = nrows + 10;
  int len = mel_lens[b];
  float mnT = fminf(fminf(ws->mnT[4 * b], ws->mnT[4 * b + 1]), fminf(ws->mnT[4 * b + 2], ws->mnT[4 * b + 3]));
  float mxT = fmaxf(fmaxf(ws->mxT[4 * b], ws->mxT[4 * b + 1]), fmaxf(ws->mxT[4 * b + 2], ws->mxT[4 * b + 3]));
  float mnO = fminf(fminf(ws->mnO[4 * b], ws->mnO[4 * b + 1]), fminf(ws->mnO[4 * b + 2], ws->mnO[4 * b + 3]));
  float mxO = fmaxf(fmaxf(ws->mxO[4 * b], ws->mxO[4 * b + 1]), fmaxf(ws->mxO[4 * b + 2], ws->mxO[4 * b + 3]));
  if (len < 2048) { mxT = fmaxf(mxT, 0.f); mxO = fmaxf(mxO, 0.f); }  // where(mask,x,0) max
  float sT = 1.0f / (mxT - mnT + 1e-8f);
  float sO = 1.0f / (mxO - mnO + 1e-8f);
  const float* po = deco + (size_t)b * 2048 * 80;
  const float* pt = dect + (size_t)b * 2048 * 80;

  // Phase A: column conv (width 80 -> 70) for nin input rows, 5 channels
  for (int p = tid; p < nin * 70; p += 256) {
    int r = p / 70, j = p - 70 * r;
    int grow = r0 + r;
    float s0 = 0, s1 = 0, s2 = 0, s3 = 0, s4 = 0;
    if (grow < len) {  // masked rows are exactly 0 -> all sums 0, skip loads
      const float* ro = po + (size_t)grow * 80 + j;
      const float* rt = pt + (size_t)grow * 80 + j;
#pragma unroll
      for (int k = 0; k < 11; ++k) {
        float tn = (rt[k] - mnT) * sT;
        float on = (ro[k] - mnO) * sO;
        float g = G11[k];
        s0 = fmaf(g, tn, s0);
        s1 = fmaf(g, on, s1);
        s2 = fmaf(g * tn, tn, s2);
        s3 = fmaf(g * on, on, s3);
        s4 = fmaf(g * tn, on, s4);
      }
    }
    cc[p] = s0; cc[2940 + p] = s1; cc[2 * 2940 + p] = s2;
    cc[3 * 2940 + p] = s3; cc[4 * 2940 + p] = s4;
  }
  __syncthreads();

  // Phase B: row conv + SSIM formula + accumulate
  float acc = 0.f;
  for (int q = tid; q < nrows * 70; q += 256) {
    int i = q / 70, j = q - 70 * i;
    float mx = 0, my = 0, xx = 0, yy = 0, xy = 0;
#pragma unroll
    for (int k = 0; k < 11; ++k) {
      float g = G11[k];
      int o = (i + k) * 70 + j;
      mx = fmaf(g, cc[o], mx);
      my = fmaf(g, cc[2940 + o], my);
      xx = fmaf(g, cc[2 * 2940 + o], xx);
      yy = fmaf(g, cc[3 * 2940 + o], yy);
      xy = fmaf(g, cc[4 * 2940 + o], xy);
    }
    float vx = xx - mx * mx, vy = yy - my * my, vxy = xy - mx * my;
    float cs = (2.f * vxy + 9e-4f) / (vx + vy + 9e-4f);
    float lum = (2.f * mx * my + 1e-4f) / (mx * mx + my * my + 1e-4f);
    acc += lum * cs;
  }
  for (int o = 32; o; o >>= 1) acc += __shfl_xor(acc, o);
  if ((tid & 63) == 0) R[tid >> 6] = acc;
  __syncthreads();
  if (tid == 0) atomicAdd(&ws->ssim_sum, (double)(R[0] + R[1] + R[2] + R[3]));
}

// ---------------- K3: finalize scalar ----------------
__global__ __launch_bounds__(256) void altts_k3(
    const int* __restrict__ mel_lens, const int* __restrict__ inp_lens,
    Ws* __restrict__ ws, float* __restrict__ out) {
  __shared__ double LD[4][4];
  int tid = threadIdx.x;
  double sp = ws->spec_part[tid];
  double md = 0.0, ml = 0.0, il = 0.0;
  if (tid < 64) {
    md = (double)ws->mdn_val[tid];
    ml = (double)mel_lens[tid];
    il = (double)inp_lens[tid];
  }
  for (int o = 32; o; o >>= 1) {
    sp += __shfl_xor(sp, o);
    md += __shfl_xor(md, o);
    ml += __shfl_xor(ml, o);
    il += __shfl_xor(il, o);
  }
  int w = tid >> 6;
  if ((tid & 63) == 0) { LD[w][0] = sp; LD[w][1] = md; LD[w][2] = ml; LD[w][3] = il; }
  __syncthreads();
  if (tid == 0) {
    sp = LD[0][0] + LD[1][0] + LD[2][0] + LD[3][0];
    md = LD[0][1] + LD[1][1] + LD[2][1] + LD[3][1];
    ml = LD[0][2] + LD[1][2] + LD[2][2] + LD[3][2];
    il = LD[0][3] + LD[1][3] + LD[2][3] + LD[3][3];
    double spec = sp / (ml * 80.0);
    double dur = ws->dur_sum / il;
    double mdn = -(md / 64.0) / 256.0;
    double sm = ws->ssim_sum / (64.0 * 2038.0 * 70.0);
    double sl = 1.0 - sm;
    sl = sl < 0.0 ? 0.0 : (sl > 1.0 ? 1.0 : sl);
    out[0] = (float)(spec + sl + dur + mdn);
  }
}

extern "C" void kernel_launch(void* const* d_in, const int* in_sizes, int n_in,
                              void* d_out, int out_size, void* d_ws, size_t ws_size,
                              hipStream_t stream) {
  const float* logp = (const float*)d_in[0];
  const float* deco = (const float*)d_in[1];
  const float* dect = (const float*)d_in[2];
  const float* duro = (const float*)d_in[3];
  const float* durt = (const float*)d_in[4];
  const int* mel_lens = (const int*)d_in[5];
  const int* inp_lens = (const int*)d_in[6];
  Ws* ws = (Ws*)d_ws;
  // Split the serial MDN chain across K1/K2 (checkpoint in ws) so its second
  // half overlaps the SSIM conv. If ws is too small for the checkpoint, run
  // the whole chain in K2 (split=0).
  int split = (ws_size >= sizeof(Ws)) ? 1023 : 0;
  hipLaunchKernelGGL(altts_k1, dim3(321), dim3(256), 0, stream,
                     logp, deco, dect, duro, durt, mel_lens, inp_lens, ws, split);
  hipLaunchKernelGGL(altts_k2, dim3(64 + 64 * 64), dim3(256), 0, stream,
                     logp, deco, dect, mel_lens, inp_lens, ws, split);
  hipLaunchKernelGGL(altts_k3, dim3(1), dim3(256), 0, stream,
                     mel_lens, inp_lens, ws, (float*)d_out);
}

// Round 4
// 227.941 us; speedup vs baseline: 2.4147x; 1.1835x over previous
//
#include <hip/hip_runtime.h>
#include <math.h>

#define INV_LN2 1.44269504088896f
#define LN2     0.693147180559945f
#define NEG2    (-14426.9504f)          // -10000 * INV_LN2
#define EPS2    (1.44269504e-4f)        // 1e-4 * INV_LN2
#define TILE    32
#define LSTR    260                      // LDS row stride (floats); 260*4=1040B, 16B-aligned rows
#define SMEM_FLOATS (2 * TILE * LSTR)    // 16640 floats = 66560 B (double buffer)

// Problem dims (fixed): B=64, T_seq=256, T_mel=2048, D=80; SSIM out = 2038 x 70

struct Ws {
  double ssim_sum;
  double dur_sum;
  double spec_part[256];
  float  mdn_val[64];       // alpha_last per batch (natural-log domain)
  float  mnT[256], mxT[256], mnO[256], mxO[256];
  float  alpha[64 * 256];   // MDN checkpoint (log2 domain)
};

__device__ __forceinline__ float lae2(float a, float b) {
  // log2-domain logaddexp: max + log2(1 + 2^-|a-b|)
  float m = fmaxf(a, b);
  float d = fabsf(a - b);
  return m + __builtin_amdgcn_logf(1.0f + __builtin_amdgcn_exp2f(-d));
}

// Tile-pipelined MDN recursion, steps ts..te (inclusive), log2 domain.
// Block: wave 0 (tid<64) computes (4 states/lane, contiguous); waves 1-3 load
// 32-step tiles of logp[b] transposed into LDS [t][s] (stride LSTR), with the
// lp*INV_LN2+EPS2 prefold done loader-side. Double-buffered; tiles 32-aligned.
__device__ void mdn_tiles(const float* __restrict__ logp_b, float* smemf,
                          float& a0, float& a1, float& a2, float& a3,
                          int ts, int te) {
  const int tid = threadIdx.x;
  const int kb0 = ts >> 5, kb1 = te >> 5;

  auto load_tile = [&](int kb) {
    if (tid < 64) return;               // loader waves only
    const int ltid = tid - 64;          // 0..191
    float* dst = smemf + ((kb - kb0) & 1) * (TILE * LSTR);
    const int tb = kb << 5;             // aligned tile base (<=2016, always in-bounds)
    float4 gl[11];
#pragma unroll
    for (int it = 0; it < 11; ++it) {   // 2048 float4 loads over 192 lanes
      int i = ltid + it * 192;
      if (i < 2048) {
        int s = i >> 3, e = i & 7;
        gl[it] = *(const float4*)(logp_b + (size_t)s * 2048 + tb + 4 * e);
      }
    }
#pragma unroll
    for (int it = 0; it < 11; ++it) {
      int i = ltid + it * 192;
      if (i < 2048) {
        int s = i >> 3, e = i & 7;
        float* d = dst + (4 * e) * LSTR + s;   // transpose scatter (~4-way bank)
        d[0]        = fmaf(gl[it].x, INV_LN2, EPS2);
        d[LSTR]     = fmaf(gl[it].y, INV_LN2, EPS2);
        d[2 * LSTR] = fmaf(gl[it].z, INV_LN2, EPS2);
        d[3 * LSTR] = fmaf(gl[it].w, INV_LN2, EPS2);
      }
    }
  };

  auto STEP = [&](const float4& g) {
    float am1 = __shfl_up(a3, 1u);
    am1 = (tid == 0) ? NEG2 : am1;
    float n0 = lae2(a0, am1) + g.x;
    float n1 = lae2(a1, a0)  + g.y;
    float n2 = lae2(a2, a1)  + g.z;
    float n3 = lae2(a3, a2)  + g.w;
    a0 = n0; a1 = n1; a2 = n2; a3 = n3;
  };

  load_tile(kb0);
  __syncthreads();
  for (int kb = kb0; kb <= kb1; ++kb) {
    if (kb + 1 <= kb1) load_tile(kb + 1);
    if (tid < 64) {
      __builtin_amdgcn_s_setprio(1);
      const float* src = smemf + ((kb - kb0) & 1) * (TILE * LSTR) + 4 * tid;
      const int tb = kb << 5;
      int t0 = ts - tb; t0 = t0 < 0 ? 0 : t0;
      int t1 = te - tb; t1 = t1 > 31 ? 31 : t1;
      float4 g = *(const float4*)(src + t0 * LSTR);  // conflict-free ds_read_b128
      if (t0 == 0 && t1 == 31) {
#pragma unroll 4
        for (int tau = 0; tau < 32; ++tau) {
          float4 gn = g;
          if (tau + 1 < 32) gn = *(const float4*)(src + (tau + 1) * LSTR);
          STEP(g);
          g = gn;
        }
      } else {
        for (int tau = t0; tau <= t1; ++tau) {
          float4 gn = g;
          if (tau + 1 <= t1) gn = *(const float4*)(src + (tau + 1) * LSTR);
          STEP(g);
          g = gn;
        }
      }
      __builtin_amdgcn_s_setprio(0);
    }
    __syncthreads();
  }
}

// ---------------- K1: MDN first half || min/max + spec MSE || dur ----------------
__global__ __launch_bounds__(256) void altts_k1(
    const float* __restrict__ logp,
    const float* __restrict__ deco, const float* __restrict__ dect,
    const float* __restrict__ duro, const float* __restrict__ durt,
    const int* __restrict__ mel_lens, const int* __restrict__ inp_lens,
    Ws* __restrict__ ws, int split) {
  __shared__ float smemf[SMEM_FLOATS];
  int bid = blockIdx.x;
  int tid = threadIdx.x;

  if (bid < 64) {  // MDN part 1 (steps 1..min(split,T)) — block-uniform path
    if (split <= 0) return;
    int b = bid;
    int T = mel_lens[b] - 1;
    const float* logp_b = logp + (size_t)b * 256 * 2048;
    float a0 = NEG2, a1 = NEG2, a2 = NEG2, a3 = NEG2;
    if (tid == 0) a0 = logp_b[0] * INV_LN2;
    int te = T < split ? T : split;
    mdn_tiles(logp_b, smemf, a0, a1, a2, a3, 1, te);
    if (tid < 64) {
      float* ck = ws->alpha + b * 256 + 4 * tid;
      ck[0] = a0; ck[1] = a1; ck[2] = a2; ck[3] = a3;
      if (T <= split) {
        int ss_ = inp_lens[b] - 1;
        if ((ss_ >> 2) == tid) {
          int e = ss_ & 3;
          float v = (e == 0) ? a0 : (e == 1) ? a1 : (e == 2) ? a2 : a3;
          ws->mdn_val[b] = v * LN2;
        }
      }
    }
    return;
  }

  float (*L)[4] = (float(*)[4])smemf;  // [5][4] carve

  if (bid < 320) {  // min/max + spec partial: 4 blocks per batch, 512 rows each
    int idx = bid - 64, b = idx >> 2, part = idx & 3;
    int len = mel_lens[b];
    int rbeg = part * 512;
    int rcnt = len - rbeg; rcnt = rcnt < 0 ? 0 : (rcnt > 512 ? 512 : rcnt);
    float mnT = __builtin_inff(), mxT = -__builtin_inff();
    float mnO = __builtin_inff(), mxO = -__builtin_inff();
    float ssum = 0.f;
    if (rcnt > 0) {
      const float4* po = (const float4*)(deco + ((size_t)(b * 2048 + rbeg)) * 80);
      const float4* pt = (const float4*)(dect + ((size_t)(b * 2048 + rbeg)) * 80);
      int n4 = rcnt * 20;
      for (int i = tid; i < n4; i += 256) {
        float4 vo = po[i], vt = pt[i];
        mnO = fminf(mnO, fminf(fminf(vo.x, vo.y), fminf(vo.z, vo.w)));
        mxO = fmaxf(mxO, fmaxf(fmaxf(vo.x, vo.y), fmaxf(vo.z, vo.w)));
        mnT = fminf(mnT, fminf(fminf(vt.x, vt.y), fminf(vt.z, vt.w)));
        mxT = fmaxf(mxT, fmaxf(fmaxf(vt.x, vt.y), fmaxf(vt.z, vt.w)));
        float dx = vo.x - vt.x, dy = vo.y - vt.y, dz = vo.z - vt.z, dw = vo.w - vt.w;
        ssum += dx * dx + dy * dy + dz * dz + dw * dw;
      }
    }
    for (int o = 32; o; o >>= 1) {
      mnT = fminf(mnT, __shfl_xor(mnT, o));
      mxT = fmaxf(mxT, __shfl_xor(mxT, o));
      mnO = fminf(mnO, __shfl_xor(mnO, o));
      mxO = fmaxf(mxO, __shfl_xor(mxO, o));
      ssum += __shfl_xor(ssum, o);
    }
    int w = tid >> 6;
    if ((tid & 63) == 0) { L[0][w] = mnT; L[1][w] = mxT; L[2][w] = mnO; L[3][w] = mxO; L[4][w] = ssum; }
    __syncthreads();
    if (tid == 0) {
      mnT = fminf(fminf(L[0][0], L[0][1]), fminf(L[0][2], L[0][3]));
      mxT = fmaxf(fmaxf(L[1][0], L[1][1]), fmaxf(L[1][2], L[1][3]));
      mnO = fminf(fminf(L[2][0], L[2][1]), fminf(L[2][2], L[2][3]));
      mxO = fmaxf(fmaxf(L[3][0], L[3][1]), fmaxf(L[3][2], L[3][3]));
      ssum = L[4][0] + L[4][1] + L[4][2] + L[4][3];
      ws->mnT[idx] = mnT; ws->mxT[idx] = mxT; ws->mnO[idx] = mnO; ws->mxO[idx] = mxO;
      ws->spec_part[idx] = (double)ssum;
    }
    return;
  }

  // dur MSE block + zero the ssim accumulator
  {
    float ssum = 0.f;
    for (int i = tid; i < 64 * 256; i += 256) {
      int b2 = i >> 8, s2 = i & 255;
      if (s2 < inp_lens[b2]) { float d = duro[i] - durt[i]; ssum += d * d; }
    }
    for (int o = 32; o; o >>= 1) ssum += __shfl_xor(ssum, o);
    int w = tid >> 6;
    if ((tid & 63) == 0) L[4][w] = ssum;
    __syncthreads();
    if (tid == 0) {
      ws->dur_sum = (double)(L[4][0] + L[4][1] + L[4][2] + L[4][3]);
      ws->ssim_sum = 0.0;
    }
  }
}

// ---------------- K2: MDN second half || SSIM conv tiles ----------------
constexpr float G11[11] = {
  0.00102838f, 0.00759876f, 0.03600077f, 0.10936070f, 0.21300554f,
  0.26601172f,
  0.21300554f, 0.10936070f, 0.03600077f, 0.00759876f, 0.00102838f};

__global__ __launch_bounds__(256) void altts_k2(
    const float* __restrict__ logp,
    const float* __restrict__ deco, const float* __restrict__ dect,
    const int* __restrict__ mel_lens, const int* __restrict__ inp_lens,
    Ws* __restrict__ ws, int split) {
  __shared__ float smemf[SMEM_FLOATS];
  int bid = blockIdx.x, tid = threadIdx.x;

  if (bid < 64) {  // MDN part 2 (steps split+1..T) — block-uniform path
    int b = bid;
    int T = mel_lens[b] - 1;
    if (split > 0 && T <= split) return;  // already recorded in k1
    const float* logp_b = logp + (size_t)b * 256 * 2048;
    float a0 = NEG2, a1 = NEG2, a2 = NEG2, a3 = NEG2;
    int ts;
    if (split > 0) {
      if (tid < 64) {
        const float* ck = ws->alpha + b * 256 + 4 * tid;
        a0 = ck[0]; a1 = ck[1]; a2 = ck[2]; a3 = ck[3];
      }
      ts = split + 1;
    } else {
      if (tid == 0) a0 = logp_b[0] * INV_LN2;
      ts = 1;
    }
    mdn_tiles(logp_b, smemf, a0, a1, a2, a3, ts, T);
    if (tid < 64) {
      int ss_ = inp_lens[b] - 1;
      if ((ss_ >> 2) == tid) {
        int e = ss_ & 3;
        float v = (e == 0) ? a0 : (e == 1) ? a1 : (e == 2) ? a2 : a3;
        ws->mdn_val[b] = v * LN2;
      }
    }
    return;
  }

  // SSIM conv tile: 64 tiles of 32 output rows per batch
  float* cc = smemf;          // [5][42][70] = 14700 floats
  float* R  = smemf + 14700;  // [4]
  int cix = bid - 64;
  int b = cix >> 6, tile = cix & 63;
  int r0 = tile * 32;
  int nrows = 2038 - r0; nrows = nrows > 32 ? 32 : nrows;
  int nin = nrows + 10;
  int len = mel_lens[b];
  float mnT = fminf(fminf(ws->mnT[4 * b], ws->mnT[4 * b + 1]), fminf(ws->mnT[4 * b + 2], ws->mnT[4 * b + 3]));
  float mxT = fmaxf(fmaxf(ws->mxT[4 * b], ws->mxT[4 * b + 1]), fmaxf(ws->mxT[4 * b + 2], ws->mxT[4 * b + 3]));
  float mnO = fminf(fminf(ws->mnO[4 * b], ws->mnO[4 * b + 1]), fminf(ws->mnO[4 * b + 2], ws->mnO[4 * b + 3]));
  float mxO = fmaxf(fmaxf(ws->mxO[4 * b], ws->mxO[4 * b + 1]), fmaxf(ws->mxO[4 * b + 2], ws->mxO[4 * b + 3]));
  if (len < 2048) { mxT = fmaxf(mxT, 0.f); mxO = fmaxf(mxO, 0.f); }
  float sT = 1.0f / (mxT - mnT + 1e-8f);
  float sO = 1.0f / (mxO - mnO + 1e-8f);
  const float* po = deco + (size_t)b * 2048 * 80;
  const float* pt = dect + (size_t)b * 2048 * 80;

  // Phase A: column conv (width 80 -> 70) for nin input rows, 5 channels
  for (int p = tid; p < nin * 70; p += 256) {
    int r = p / 70, j = p - 70 * r;
    int grow = r0 + r;
    float s0 = 0, s1 = 0, s2 = 0, s3 = 0, s4 = 0;
    if (grow < len) {
      const float* ro = po + (size_t)grow * 80 + j;
      const float* rt = pt + (size_t)grow * 80 + j;
#pragma unroll
      for (int k = 0; k < 11; ++k) {
        float tn = (rt[k] - mnT) * sT;
        float on = (ro[k] - mnO) * sO;
        float g = G11[k];
        s0 = fmaf(g, tn, s0);
        s1 = fmaf(g, on, s1);
        s2 = fmaf(g * tn, tn, s2);
        s3 = fmaf(g * on, on, s3);
        s4 = fmaf(g * tn, on, s4);
      }
    }
    cc[p] = s0; cc[2940 + p] = s1; cc[2 * 2940 + p] = s2;
    cc[3 * 2940 + p] = s3; cc[4 * 2940 + p] = s4;
  }
  __syncthreads();

  // Phase B: row conv + SSIM formula + accumulate
  float acc = 0.f;
  for (int q = tid; q < nrows * 70; q += 256) {
    int i = q / 70, j = q - 70 * i;
    float mx = 0, my = 0, xx = 0, yy = 0, xy = 0;
#pragma unroll
    for (int k = 0; k < 11; ++k) {
      float g = G11[k];
      int o = (i + k) * 70 + j;
      mx = fmaf(g, cc[o], mx);
      my = fmaf(g, cc[2940 + o], my);
      xx = fmaf(g, cc[2 * 2940 + o], xx);
      yy = fmaf(g, cc[3 * 2940 + o], yy);
      xy = fmaf(g, cc[4 * 2940 + o], xy);
    }
    float vx = xx - mx * mx, vy = yy - my * my, vxy = xy - mx * my;
    float cs = (2.f * vxy + 9e-4f) / (vx + vy + 9e-4f);
    float lum = (2.f * mx * my + 1e-4f) / (mx * mx + my * my + 1e-4f);
    acc += lum * cs;
  }
  for (int o = 32; o; o >>= 1) acc += __shfl_xor(acc, o);
  if ((tid & 63) == 0) R[tid >> 6] = acc;
  __syncthreads();
  if (tid == 0) atomicAdd(&ws->ssim_sum, (double)(R[0] + R[1] + R[2] + R[3]));
}

// ---------------- K3: finalize scalar ----------------
__global__ __launch_bounds__(256) void altts_k3(
    const int* __restrict__ mel_lens, const int* __restrict__ inp_lens,
    Ws* __restrict__ ws, float* __restrict__ out) {
  __shared__ double LD[4][4];
  int tid = threadIdx.x;
  double sp = ws->spec_part[tid];
  double md = 0.0, ml = 0.0, il = 0.0;
  if (tid < 64) {
    md = (double)ws->mdn_val[tid];
    ml = (double)mel_lens[tid];
    il = (double)inp_lens[tid];
  }
  for (int o = 32; o; o >>= 1) {
    sp += __shfl_xor(sp, o);
    md += __shfl_xor(md, o);
    ml += __shfl_xor(ml, o);
    il += __shfl_xor(il, o);
  }
  int w = tid >> 6;
  if ((tid & 63) == 0) { LD[w][0] = sp; LD[w][1] = md; LD[w][2] = ml; LD[w][3] = il; }
  __syncthreads();
  if (tid == 0) {
    sp = LD[0][0] + LD[1][0] + LD[2][0] + LD[3][0];
    md = LD[0][1] + LD[1][1] + LD[2][1] + LD[3][1];
    ml = LD[0][2] + LD[1][2] + LD[2][2] + LD[3][2];
    il = LD[0][3] + LD[1][3] + LD[2][3] + LD[3][3];
    double spec = sp / (ml * 80.0);
    double dur = ws->dur_sum / il;
    double mdn = -(md / 64.0) / 256.0;
    double sm = ws->ssim_sum / (64.0 * 2038.0 * 70.0);
    double sl = 1.0 - sm;
    sl = sl < 0.0 ? 0.0 : (sl > 1.0 ? 1.0 : sl);
    out[0] = (float)(spec + sl + dur + mdn);
  }
}

extern "C" void kernel_launch(void* const* d_in, const int* in_sizes, int n_in,
                              void* d_out, int out_size, void* d_ws, size_t ws_size,
                              hipStream_t stream) {
  const float* logp = (const float*)d_in[0];
  const float* deco = (const float*)d_in[1];
  const float* dect = (const float*)d_in[2];
  const float* duro = (const float*)d_in[3];
  const float* durt = (const float*)d_in[4];
  const int* mel_lens = (const int*)d_in[5];
  const int* inp_lens = (const int*)d_in[6];
  Ws* ws = (Ws*)d_ws;
  int split = (ws_size >= sizeof(Ws)) ? 1023 : 0;
  hipLaunchKernelGGL(altts_k1, dim3(321), dim3(256), 0, stream,
                     logp, deco, dect, duro, durt, mel_lens, inp_lens, ws, split);
  hipLaunchKernelGGL(altts_k2, dim3(64 + 64 * 64), dim3(256), 0, stream,
                     logp, deco, dect, mel_lens, inp_lens, ws, split);
  hipLaunchKernelGGL(altts_k3, dim3(1), dim3(256), 0, stream,
                     mel_lens, inp_lens, ws, (float*)d_out);
}

// Round 5
// 201.861 us; speedup vs baseline: 2.7266x; 1.1292x over previous
//
#include <hip/hip_runtime.h>
#include <math.h>

#define INV_LN2 1.44269504088896f
#define LN2     0.693147180559945f
#define NEG2    (-14426.9504f)          // -10000 * INV_LN2
#define EPS2    (1.44269504e-4f)        // 1e-4 * INV_LN2
#define TILE    32
#define LSTR    260                      // LDS row stride (floats); 260*4=1040B, 16B-aligned rows
#define SMEM_FLOATS (2 * TILE * LSTR)    // 16640 floats = 66560 B (double buffer)

// Problem dims (fixed): B=64, T_seq=256, T_mel=2048, D=80; SSIM out = 2038 x 70

struct Ws {
  double ssim_sum;
  double dur_sum;
  double spec_part[256];
  float  mdn_val[64];       // alpha_last per batch (natural-log domain)
  float  mnT[256], mxT[256], mnO[256], mxO[256];
  float  alpha[64 * 256];   // MDN checkpoint (log2 domain)
};

// log2-domain logaddexp with pre-folded additive term g:
//   lae2g(a,b,g) = max(a,b) + g + log2(1 + 2^-|a-b|)
// (m+g) computed in parallel with the exp2/log2 chain.
__device__ __forceinline__ float lae2g(float a, float b, float g) {
  float m = fmaxf(a, b);
  float d = fabsf(a - b);
  float base = m + g;
  return base + __builtin_amdgcn_logf(1.0f + __builtin_amdgcn_exp2f(-d));
}

// Tile-pipelined MDN recursion, steps ts..te (inclusive), log2 domain.
// Block: wave 0 (tid<64) computes (4 states/lane, contiguous); waves 1-3 load
// 32-step tiles of logp[b] transposed into LDS [t][s] (stride LSTR), with the
// lp*INV_LN2+EPS2 prefold done loader-side. Double-buffered; tiles 32-aligned.
// Compute wave: DPP wave_shr:1 for the cross-lane shift (no LDS op), and all
// 32 ds_read_b128 of a tile hoisted into registers before the 32-step unroll.
__device__ void mdn_tiles(const float* __restrict__ logp_b, float* smemf,
                          float& a0, float& a1, float& a2, float& a3,
                          int ts, int te) {
  const int tid = threadIdx.x;
  const int kb0 = ts >> 5, kb1 = te >> 5;

  auto load_tile = [&](int kb) {
    if (tid < 64) return;               // loader waves only
    const int ltid = tid - 64;          // 0..191
    float* dst = smemf + ((kb - kb0) & 1) * (TILE * LSTR);
    const int tb = kb << 5;             // aligned tile base (<=2016, always in-bounds)
    float4 gl[11];
#pragma unroll
    for (int it = 0; it < 11; ++it) {   // 2048 float4 loads over 192 lanes
      int i = ltid + it * 192;
      if (i < 2048) {
        int s = i >> 3, e = i & 7;
        gl[it] = *(const float4*)(logp_b + (size_t)s * 2048 + tb + 4 * e);
      }
    }
#pragma unroll
    for (int it = 0; it < 11; ++it) {
      int i = ltid + it * 192;
      if (i < 2048) {
        int s = i >> 3, e = i & 7;
        float* d = dst + (4 * e) * LSTR + s;   // transpose scatter
        d[0]        = fmaf(gl[it].x, INV_LN2, EPS2);
        d[LSTR]     = fmaf(gl[it].y, INV_LN2, EPS2);
        d[2 * LSTR] = fmaf(gl[it].z, INV_LN2, EPS2);
        d[3 * LSTR] = fmaf(gl[it].w, INV_LN2, EPS2);
      }
    }
  };

  auto STEP = [&](float gx, float gy, float gz, float gw) {
    // am1 = lane-1's a3 (lane 0 -> NEG2): DPP wave_shr:1, pure VALU
    int up = __builtin_amdgcn_update_dpp(__float_as_int(NEG2),
                                         __float_as_int(a3),
                                         0x138 /*wave_shr:1*/, 0xF, 0xF, false);
    float am1 = __int_as_float(up);
    float n0 = lae2g(a0, am1, gx);
    float n1 = lae2g(a1, a0,  gy);
    float n2 = lae2g(a2, a1,  gz);
    float n3 = lae2g(a3, a2,  gw);
    a0 = n0; a1 = n1; a2 = n2; a3 = n3;
  };

  load_tile(kb0);
  __syncthreads();
  for (int kb = kb0; kb <= kb1; ++kb) {
    if (kb + 1 <= kb1) load_tile(kb + 1);
    if (tid < 64) {
      __builtin_amdgcn_s_setprio(1);
      const float* src = smemf + ((kb - kb0) & 1) * (TILE * LSTR) + 4 * tid;
      const int tb = kb << 5;
      int t0 = ts - tb; t0 = t0 < 0 ? 0 : t0;
      int t1 = te - tb; t1 = t1 > 31 ? 31 : t1;
      if (t0 == 0 && t1 == 31) {
        float4 G[32];
#pragma unroll
        for (int i = 0; i < 32; ++i)
          G[i] = *(const float4*)(src + i * LSTR);   // 32 pipelined ds_read_b128
#pragma unroll
        for (int i = 0; i < 32; ++i)
          STEP(G[i].x, G[i].y, G[i].z, G[i].w);
      } else {
        for (int tau = t0; tau <= t1; ++tau) {
          float4 g = *(const float4*)(src + tau * LSTR);
          STEP(g.x, g.y, g.z, g.w);
        }
      }
      __builtin_amdgcn_s_setprio(0);
    }
    __syncthreads();
  }
}

// ---------------- K1: MDN first half || min/max + spec MSE || dur ----------------
__global__ __launch_bounds__(256) void altts_k1(
    const float* __restrict__ logp,
    const float* __restrict__ deco, const float* __restrict__ dect,
    const float* __restrict__ duro, const float* __restrict__ durt,
    const int* __restrict__ mel_lens, const int* __restrict__ inp_lens,
    Ws* __restrict__ ws, int split) {
  __shared__ float smemf[SMEM_FLOATS];
  int bid = blockIdx.x;
  int tid = threadIdx.x;

  if (bid < 64) {  // MDN part 1 (steps 1..min(split,T)) — block-uniform path
    if (split <= 0) return;
    int b = bid;
    int T = mel_lens[b] - 1;
    const float* logp_b = logp + (size_t)b * 256 * 2048;
    float a0 = NEG2, a1 = NEG2, a2 = NEG2, a3 = NEG2;
    if (tid == 0) a0 = logp_b[0] * INV_LN2;
    int te = T < split ? T : split;
    mdn_tiles(logp_b, smemf, a0, a1, a2, a3, 1, te);
    if (tid < 64) {
      float* ck = ws->alpha + b * 256 + 4 * tid;
      ck[0] = a0; ck[1] = a1; ck[2] = a2; ck[3] = a3;
      if (T <= split) {
        int ss_ = inp_lens[b] - 1;
        if ((ss_ >> 2) == tid) {
          int e = ss_ & 3;
          float v = (e == 0) ? a0 : (e == 1) ? a1 : (e == 2) ? a2 : a3;
          ws->mdn_val[b] = v * LN2;
        }
      }
    }
    return;
  }

  float (*L)[4] = (float(*)[4])smemf;  // [5][4] carve

  if (bid < 320) {  // min/max + spec partial: 4 blocks per batch, 512 rows each
    int idx = bid - 64, b = idx >> 2, part = idx & 3;
    int len = mel_lens[b];
    int rbeg = part * 512;
    int rcnt = len - rbeg; rcnt = rcnt < 0 ? 0 : (rcnt > 512 ? 512 : rcnt);
    float mnT = __builtin_inff(), mxT = -__builtin_inff();
    float mnO = __builtin_inff(), mxO = -__builtin_inff();
    float ssum = 0.f;
    if (rcnt > 0) {
      const float4* po = (const float4*)(deco + ((size_t)(b * 2048 + rbeg)) * 80);
      const float4* pt = (const float4*)(dect + ((size_t)(b * 2048 + rbeg)) * 80);
      int n4 = rcnt * 20;
      for (int i = tid; i < n4; i += 256) {
        float4 vo = po[i], vt = pt[i];
        mnO = fminf(mnO, fminf(fminf(vo.x, vo.y), fminf(vo.z, vo.w)));
        mxO = fmaxf(mxO, fmaxf(fmaxf(vo.x, vo.y), fmaxf(vo.z, vo.w)));
        mnT = fminf(mnT, fminf(fminf(vt.x, vt.y), fminf(vt.z, vt.w)));
        mxT = fmaxf(mxT, fmaxf(fmaxf(vt.x, vt.y), fmaxf(vt.z, vt.w)));
        float dx = vo.x - vt.x, dy = vo.y - vt.y, dz = vo.z - vt.z, dw = vo.w - vt.w;
        ssum += dx * dx + dy * dy + dz * dz + dw * dw;
      }
    }
    for (int o = 32; o; o >>= 1) {
      mnT = fminf(mnT, __shfl_xor(mnT, o));
      mxT = fmaxf(mxT, __shfl_xor(mxT, o));
      mnO = fminf(mnO, __shfl_xor(mnO, o));
      mxO = fmaxf(mxO, __shfl_xor(mxO, o));
      ssum += __shfl_xor(ssum, o);
    }
    int w = tid >> 6;
    if ((tid & 63) == 0) { L[0][w] = mnT; L[1][w] = mxT; L[2][w] = mnO; L[3][w] = mxO; L[4][w] = ssum; }
    __syncthreads();
    if (tid == 0) {
      mnT = fminf(fminf(L[0][0], L[0][1]), fminf(L[0][2], L[0][3]));
      mxT = fmaxf(fmaxf(L[1][0], L[1][1]), fmaxf(L[1][2], L[1][3]));
      mnO = fminf(fminf(L[2][0], L[2][1]), fminf(L[2][2], L[2][3]));
      mxO = fmaxf(fmaxf(L[3][0], L[3][1]), fmaxf(L[3][2], L[3][3]));
      ssum = L[4][0] + L[4][1] + L[4][2] + L[4][3];
      ws->mnT[idx] = mnT; ws->mxT[idx] = mxT; ws->mnO[idx] = mnO; ws->mxO[idx] = mxO;
      ws->spec_part[idx] = (double)ssum;
    }
    return;
  }

  // dur MSE block + zero the ssim accumulator
  {
    float ssum = 0.f;
    for (int i = tid; i < 64 * 256; i += 256) {
      int b2 = i >> 8, s2 = i & 255;
      if (s2 < inp_lens[b2]) { float d = duro[i] - durt[i]; ssum += d * d; }
    }
    for (int o = 32; o; o >>= 1) ssum += __shfl_xor(ssum, o);
    int w = tid >> 6;
    if ((tid & 63) == 0) L[4][w] = ssum;
    __syncthreads();
    if (tid == 0) {
      ws->dur_sum = (double)(L[4][0] + L[4][1] + L[4][2] + L[4][3]);
      ws->ssim_sum = 0.0;
    }
  }
}

// ---------------- K2: MDN second half || SSIM conv tiles ----------------
constexpr float G11[11] = {
  0.00102838f, 0.00759876f, 0.03600077f, 0.10936070f, 0.21300554f,
  0.26601172f,
  0.21300554f, 0.10936070f, 0.03600077f, 0.00759876f, 0.00102838f};

__global__ __launch_bounds__(256) void altts_k2(
    const float* __restrict__ logp,
    const float* __restrict__ deco, const float* __restrict__ dect,
    const int* __restrict__ mel_lens, const int* __restrict__ inp_lens,
    Ws* __restrict__ ws, int split) {
  __shared__ float smemf[SMEM_FLOATS];
  int bid = blockIdx.x, tid = threadIdx.x;

  if (bid < 64) {  // MDN part 2 (steps split+1..T) — block-uniform path
    int b = bid;
    int T = mel_lens[b] - 1;
    if (split > 0 && T <= split) return;  // already recorded in k1
    const float* logp_b = logp + (size_t)b * 256 * 2048;
    float a0 = NEG2, a1 = NEG2, a2 = NEG2, a3 = NEG2;
    int ts;
    if (split > 0) {
      if (tid < 64) {
        const float* ck = ws->alpha + b * 256 + 4 * tid;
        a0 = ck[0]; a1 = ck[1]; a2 = ck[2]; a3 = ck[3];
      }
      ts = split + 1;
    } else {
      if (tid == 0) a0 = logp_b[0] * INV_LN2;
      ts = 1;
    }
    mdn_tiles(logp_b, smemf, a0, a1, a2, a3, ts, T);
    if (tid < 64) {
      int ss_ = inp_lens[b] - 1;
      if ((ss_ >> 2) == tid) {
        int e = ss_ & 3;
        float v = (e == 0) ? a0 : (e == 1) ? a1 : (e == 2) ? a2 : a3;
        ws->mdn_val[b] = v * LN2;
      }
    }
    return;
  }

  // SSIM conv tile: 64 tiles of 32 output rows per batch
  float* cc = smemf;          // [5][42][70] = 14700 floats
  float* R  = smemf + 14700;  // [4]
  int cix = bid - 64;
  int b = cix >> 6, tile = cix & 63;
  int r0 = tile * 32;
  int nrows = 2038 - r0; nrows = nrows > 32 ? 32 : nrows;
  int nin = nrows + 10;
  int len = mel_lens[b];
  float mnT = fminf(fminf(ws->mnT[4 * b], ws->mnT[4 * b + 1]), fminf(ws->mnT[4 * b + 2], ws->mnT[4 * b + 3]));
  float mxT = fmaxf(fmaxf(ws->mxT[4 * b], ws->mxT[4 * b + 1]), fmaxf(ws->mxT[4 * b + 2], ws->mxT[4 * b + 3]));
  float mnO = fminf(fminf(ws->mnO[4 * b], ws->mnO[4 * b + 1]), fminf(ws->mnO[4 * b + 2], ws->mnO[4 * b + 3]));
  float mxO = fmaxf(fmaxf(ws->mxO[4 * b], ws->mxO[4 * b + 1]), fmaxf(ws->mxO[4 * b + 2], ws->mxO[4 * b + 3]));
  if (len < 2048) { mxT = fmaxf(mxT, 0.f); mxO = fmaxf(mxO, 0.f); }
  float sT = 1.0f / (mxT - mnT + 1e-8f);
  float sO = 1.0f / (mxO - mnO + 1e-8f);
  const float* po = deco + (size_t)b * 2048 * 80;
  const float* pt = dect + (size_t)b * 2048 * 80;

  // Phase A: column conv (width 80 -> 70) for nin input rows, 5 channels
  for (int p = tid; p < nin * 70; p += 256) {
    int r = p / 70, j = p - 70 * r;
    int grow = r0 + r;
    float s0 = 0, s1 = 0, s2 = 0, s3 = 0, s4 = 0;
    if (grow < len) {
      const float* ro = po + (size_t)grow * 80 + j;
      const float* rt = pt + (size_t)grow * 80 + j;
#pragma unroll
      for (int k = 0; k < 11; ++k) {
        float tn = (rt[k] - mnT) * sT;
        float on = (ro[k] - mnO) * sO;
        float g = G11[k];
        s0 = fmaf(g, tn, s0);
        s1 = fmaf(g, on, s1);
        s2 = fmaf(g * tn, tn, s2);
        s3 = fmaf(g * on, on, s3);
        s4 = fmaf(g * tn, on, s4);
      }
    }
    cc[p] = s0; cc[2940 + p] = s1; cc[2 * 2940 + p] = s2;
    cc[3 * 2940 + p] = s3; cc[4 * 2940 + p] = s4;
  }
  __syncthreads();

  // Phase B: row conv + SSIM formula + accumulate
  float acc = 0.f;
  for (int q = tid; q < nrows * 70; q += 256) {
    int i = q / 70, j = q - 70 * i;
    float mx = 0, my = 0, xx = 0, yy = 0, xy = 0;
#pragma unroll
    for (int k = 0; k < 11; ++k) {
      float g = G11[k];
      int o = (i + k) * 70 + j;
      mx = fmaf(g, cc[o], mx);
      my = fmaf(g, cc[2940 + o], my);
      xx = fmaf(g, cc[2 * 2940 + o], xx);
      yy = fmaf(g, cc[3 * 2940 + o], yy);
      xy = fmaf(g, cc[4 * 2940 + o], xy);
    }
    float vx = xx - mx * mx, vy = yy - my * my, vxy = xy - mx * my;
    float cs = (2.f * vxy + 9e-4f) / (vx + vy + 9e-4f);
    float lum = (2.f * mx * my + 1e-4f) / (mx * mx + my * my + 1e-4f);
    acc += lum * cs;
  }
  for (int o = 32; o; o >>= 1) acc += __shfl_xor(acc, o);
  if ((tid & 63) == 0) R[tid >> 6] = acc;
  __syncthreads();
  if (tid == 0) atomicAdd(&ws->ssim_sum, (double)(R[0] + R[1] + R[2] + R[3]));
}

// ---------------- K3: finalize scalar ----------------
__global__ __launch_bounds__(256) void altts_k3(
    const int* __restrict__ mel_lens, const int* __restrict__ inp_lens,
    Ws* __restrict__ ws, float* __restrict__ out) {
  __shared__ double LD[4][4];
  int tid = threadIdx.x;
  double sp = ws->spec_part[tid];
  double md = 0.0, ml = 0.0, il = 0.0;
  if (tid < 64) {
    md = (double)ws->mdn_val[tid];
    ml = (double)mel_lens[tid];
    il = (double)inp_lens[tid];
  }
  for (int o = 32; o; o >>= 1) {
    sp += __shfl_xor(sp, o);
    md += __shfl_xor(md, o);
    ml += __shfl_xor(ml, o);
    il += __shfl_xor(il, o);
  }
  int w = tid >> 6;
  if ((tid & 63) == 0) { LD[w][0] = sp; LD[w][1] = md; LD[w][2] = ml; LD[w][3] = il; }
  __syncthreads();
  if (tid == 0) {
    sp = LD[0][0] + LD[1][0] + LD[2][0] + LD[3][0];
    md = LD[0][1] + LD[1][1] + LD[2][1] + LD[3][1];
    ml = LD[0][2] + LD[1][2] + LD[2][2] + LD[3][2];
    il = LD[0][3] + LD[1][3] + LD[2][3] + LD[3][3];
    double spec = sp / (ml * 80.0);
    double dur = ws->dur_sum / il;
    double mdn = -(md / 64.0) / 256.0;
    double sm = ws->ssim_sum / (64.0 * 2038.0 * 70.0);
    double sl = 1.0 - sm;
    sl = sl < 0.0 ? 0.0 : (sl > 1.0 ? 1.0 : sl);
    out[0] = (float)(spec + sl + dur + mdn);
  }
}

extern "C" void kernel_launch(void* const* d_in, const int* in_sizes, int n_in,
                              void* d_out, int out_size, void* d_ws, size_t ws_size,
                              hipStream_t stream) {
  const float* logp = (const float*)d_in[0];
  const float* deco = (const float*)d_in[1];
  const float* dect = (const float*)d_in[2];
  const float* duro = (const float*)d_in[3];
  const float* durt = (const float*)d_in[4];
  const int* mel_lens = (const int*)d_in[5];
  const int* inp_lens = (const int*)d_in[6];
  Ws* ws = (Ws*)d_ws;
  int split = (ws_size >= sizeof(Ws)) ? 1023 : 0;
  hipLaunchKernelGGL(altts_k1, dim3(321), dim3(256), 0, stream,
                     logp, deco, dect, duro, durt, mel_lens, inp_lens, ws, split);
  hipLaunchKernelGGL(altts_k2, dim3(64 + 64 * 64), dim3(256), 0, stream,
                     logp, deco, dect, mel_lens, inp_lens, ws, split);
  hipLaunchKernelGGL(altts_k3, dim3(1), dim3(256), 0, stream,
                     mel_lens, inp_lens, ws, (float*)d_out);
}